// Round 6
// baseline (333.293 us; speedup 1.0000x reference)
//
#include <hip/hip_runtime.h>
#include <stdint.h>

#define K_DIM 4096
#define N_DIM 4096
#define SIGMA 20.0f
#define EPSQ 1e-8f

typedef __attribute__((ext_vector_type(4))) int i32x4;

// global_load_lds width-16 helper (addrspace casts: generic->AS1 / ->AS3)
#define GLDS16(gp, lp)                                                         \
  __builtin_amdgcn_global_load_lds(                                            \
      (const __attribute__((address_space(1))) unsigned int*)(const void*)(gp),\
      (__attribute__((address_space(3))) unsigned int*)(void*)(lp), 16, 0, 0)

// s_waitcnt immediates (gfx9 encoding: vmcnt[3:0]|[15:14], exp[6:4], lgkm[11:8])
#define WAITCNT_VM8   0x0F78   // vmcnt(8), lgkm/exp = no-wait
#define WAITCNT_LGKM0 0xC07F   // lgkmcnt(0), vm/exp = no-wait

// ---------------------------------------------------------------------------
// Kernel 1: activation row quant, one row per wave (unchanged from R5).
// ---------------------------------------------------------------------------
__global__ __launch_bounds__(256) void k_rowquant(
    const float* __restrict__ x, float* __restrict__ row_scale,
    int* __restrict__ mask, int8_t* __restrict__ qx)
{
  const int wave = threadIdx.x >> 6;
  const int lane = threadIdx.x & 63;
  const int m = blockIdx.x * 4 + wave;
  const float4* xr = (const float4*)(x + (size_t)m * K_DIM);
  float4 v[16];
  float amax = 0.0f;
#pragma unroll
  for (int c = 0; c < 16; ++c) {
    v[c] = xr[lane + c * 64];
    float a0 = fabsf(v[c].x), a1 = fabsf(v[c].y);
    float a2 = fabsf(v[c].z), a3 = fabsf(v[c].w);
    amax = fmaxf(amax, fmaxf(fmaxf(a0, a1), fmaxf(a2, a3)));
    int kb = (lane + c * 64) * 4;
    if (a0 > SIGMA) mask[kb + 0] = 1;
    if (a1 > SIGMA) mask[kb + 1] = 1;
    if (a2 > SIGMA) mask[kb + 2] = 1;
    if (a3 > SIGMA) mask[kb + 3] = 1;
  }
#pragma unroll
  for (int off = 32; off > 0; off >>= 1)
    amax = fmaxf(amax, __shfl_xor(amax, off, 64));
  const float rs = fmaxf(amax / 127.0f, EPSQ);  // IEEE divide: bit-match jnp
  if (lane == 0) row_scale[m] = rs;
  uint32_t* qxo = (uint32_t*)(qx + (size_t)m * K_DIM);
#pragma unroll
  for (int c = 0; c < 16; ++c) {
    int q0 = (int)rintf(fminf(fmaxf(v[c].x / rs, -128.0f), 127.0f));
    int q1 = (int)rintf(fminf(fmaxf(v[c].y / rs, -128.0f), 127.0f));
    int q2 = (int)rintf(fminf(fmaxf(v[c].z / rs, -128.0f), 127.0f));
    int q3 = (int)rintf(fminf(fmaxf(v[c].w / rs, -128.0f), 127.0f));
    qxo[lane + c * 64] = (uint32_t)(q0 & 0xff) | ((uint32_t)(q1 & 0xff) << 8) |
                         ((uint32_t)(q2 & 0xff) << 16) | ((uint32_t)(q3 & 0xff) << 24);
  }
}

// ---------------------------------------------------------------------------
// Kernel 2: weight quant (one row per wave) + mask compaction in block 0
// (unchanged from R5). mask tested ==1 vs 0xAA poison; no pre-zero needed.
// ---------------------------------------------------------------------------
__global__ __launch_bounds__(256) void k_wquant(
    const float* __restrict__ w, const int* __restrict__ mask,
    float* __restrict__ q_scale, int8_t* __restrict__ qw,
    int* __restrict__ outlist, int* __restrict__ count)
{
  if (blockIdx.x == 0) {
    __shared__ int lcnt;
    if (threadIdx.x == 0) lcnt = 0;
    __syncthreads();
    for (int k = threadIdx.x; k < K_DIM; k += 256)
      if (mask[k] == 1) { int i = atomicAdd(&lcnt, 1); outlist[i] = k; }
    __syncthreads();
    if (threadIdx.x == 0) *count = lcnt;
  }

  const int wave = threadIdx.x >> 6;
  const int lane = threadIdx.x & 63;
  const int n = blockIdx.x * 4 + wave;
  const float4* wr = (const float4*)(w + (size_t)n * K_DIM);
  const int4* mr = (const int4*)mask;
  float4 v[16];
  float amax = 0.0f;
#pragma unroll
  for (int c = 0; c < 16; ++c) {
    float4 vv = wr[lane + c * 64];
    int4 mm = mr[lane + c * 64];
    vv.x = (mm.x == 1) ? 0.0f : vv.x;
    vv.y = (mm.y == 1) ? 0.0f : vv.y;
    vv.z = (mm.z == 1) ? 0.0f : vv.z;
    vv.w = (mm.w == 1) ? 0.0f : vv.w;
    v[c] = vv;
    amax = fmaxf(amax, fmaxf(fmaxf(fabsf(vv.x), fabsf(vv.y)),
                             fmaxf(fabsf(vv.z), fabsf(vv.w))));
  }
#pragma unroll
  for (int off = 32; off > 0; off >>= 1)
    amax = fmaxf(amax, __shfl_xor(amax, off, 64));
  const float qs = fmaxf(amax / 127.0f, EPSQ);
  if (lane == 0) q_scale[n] = qs;
  uint32_t* qwo = (uint32_t*)(qw + (size_t)n * K_DIM);
#pragma unroll
  for (int c = 0; c < 16; ++c) {
    int q0 = (int)rintf(fminf(fmaxf(v[c].x / qs, -128.0f), 127.0f));
    int q1 = (int)rintf(fminf(fmaxf(v[c].y / qs, -128.0f), 127.0f));
    int q2 = (int)rintf(fminf(fmaxf(v[c].z / qs, -128.0f), 127.0f));
    int q3 = (int)rintf(fminf(fmaxf(v[c].w / qs, -128.0f), 127.0f));
    qwo[lane + c * 64] = (uint32_t)(q0 & 0xff) | ((uint32_t)(q1 & 0xff) << 8) |
                         ((uint32_t)(q2 & 0xff) << 16) | ((uint32_t)(q3 & 0xff) << 24);
  }
}

// ---------------------------------------------------------------------------
// Kernel 3: int8 GEMM, BARRIER-FREE pipelined K-loop.
// One wave (64 thr) per block, 64x64 tile, 4x4 of mfma_i32_16x16x64.
// Double-buffered LDS (2 x 8KB), prefetch depth 2, manual s_waitcnt vmcnt(8)
// between iterations -- no __syncthreads in the loop, so no vmcnt(0) drain
// and every wave self-paces (8 independent waves/CU hide each other).
// LDS swizzle from R3 retained: c_phys = c_log ^ ((row>>1)&3) -> conflict-free
// quarter-wave ds_read_b128. Prefetch addresses wrap mod K (last 2 iters stage
// dead-but-valid data to keep the vmcnt bookkeeping uniform).
// ---------------------------------------------------------------------------
__global__ __launch_bounds__(64, 2) void k_gemm(
    const int8_t* __restrict__ qx, const int8_t* __restrict__ qw,
    const float* __restrict__ row_scale, const float* __restrict__ q_scale,
    const float* __restrict__ bias,
    const float* __restrict__ x, const float* __restrict__ w,
    const int* __restrict__ outlist, const int* __restrict__ outcount,
    float* __restrict__ out)
{
  __shared__ int8_t Abuf[2][64 * 64];   // 8 KB total
  __shared__ int8_t Bbuf[2][64 * 64];   // 8 KB
  __shared__ float xsh[64][8];          // 2 KB
  __shared__ float wsh[64][8];          // 2 KB

  const int lane = threadIdx.x;         // 0..63 (one wave)
  const int m0 = blockIdx.y * 64;
  const int n0 = blockIdx.x * 64;

  const int lrow = lane & 15;
  const int kg = lane >> 4;             // 0..3

  i32x4 acc[4][4] = {};

  // staging geometry: GLDS instr i stages rows 16i..16i+15 of a 64x64B tile;
  // lane -> row 16i+(lane>>2), phys chunk lane&3; fetches logical chunk
  // c_log = (lane&3) ^ ((lane>>3)&3)  (the (row>>1)&3 swizzle, i-independent)
  const int srow = lane >> 2;
  const int clog = (lane & 3) ^ ((lane >> 3) & 3);
  const int8_t* gA = qx + (size_t)(m0 + srow) * K_DIM + clog * 16;
  const int8_t* gB = qw + (size_t)(n0 + srow) * K_DIM + clog * 16;

  // loop-invariant swizzled LDS read offsets
  int offA[4], offB[4];
#pragma unroll
  for (int i = 0; i < 4; ++i) {
    int rA = i * 16 + lrow;
    offA[i] = rA * 64 + ((kg ^ ((rA >> 1) & 3)) * 16);
    int rB = i * 16 + lrow;
    offB[i] = rB * 64 + ((kg ^ ((rB >> 1) & 3)) * 16);
  }

#define STAGE(buf, k0)                                                        \
  {                                                                           \
    _Pragma("unroll")                                                         \
    for (int i = 0; i < 4; ++i)                                               \
      GLDS16(gA + (k0) + (size_t)i * 16 * K_DIM,                              \
             Abuf[buf] + i * 1024 + lane * 16);                               \
    _Pragma("unroll")                                                         \
    for (int i = 0; i < 4; ++i)                                               \
      GLDS16(gB + (k0) + (size_t)i * 16 * K_DIM,                              \
             Bbuf[buf] + i * 1024 + lane * 16);                               \
  }

  STAGE(0, 0);
  STAGE(1, 64);

  for (int t = 0; t < K_DIM / 64; ++t) {
    const int buf = t & 1;
    __builtin_amdgcn_s_waitcnt(WAITCNT_VM8);   // oldest 8 (this buf) landed
    __builtin_amdgcn_sched_barrier(0);         // pin ds_reads below the wait
    i32x4 af[4], bf[4];
#pragma unroll
    for (int i = 0; i < 4; ++i) af[i] = *(const i32x4*)(Abuf[buf] + offA[i]);
#pragma unroll
    for (int j = 0; j < 4; ++j) bf[j] = *(const i32x4*)(Bbuf[buf] + offB[j]);
    __builtin_amdgcn_s_waitcnt(WAITCNT_LGKM0); // frags in VGPRs; buf reusable
    __builtin_amdgcn_sched_barrier(0);
    STAGE(buf, ((t + 2) & (K_DIM / 64 - 1)) * 64);  // prefetch depth 2 (wrapped)
#pragma unroll
    for (int i = 0; i < 4; ++i)
#pragma unroll
      for (int j = 0; j < 4; ++j)
        acc[i][j] = __builtin_amdgcn_mfma_i32_16x16x64_i8(af[i], bf[j], acc[i][j], 0, 0, 0);
  }
#undef STAGE

  __syncthreads();  // drain outstanding dead prefetches before epilogue

  // ---- epilogue: stage outlier x / w slices into LDS ----
  const int cnt = *outcount;
  const int cs = cnt < 8 ? cnt : 8;
#pragma unroll
  for (int o = 0; o < 8; ++o) {
    float xv = 0.0f, wv = 0.0f;
    if (o < cs) {
      int kcol = outlist[o];
      xv = x[(size_t)(m0 + lane) * K_DIM + kcol];
      wv = w[(size_t)(n0 + lane) * K_DIM + kcol];
    }
    xsh[lane][o] = xv;
    wsh[lane][o] = wv;
  }
  __syncthreads();

  float qs[4], bv[4];
  int gn[4];
#pragma unroll
  for (int j = 0; j < 4; ++j) {
    gn[j] = n0 + j * 16 + lrow;
    qs[j] = q_scale[gn[j]];
    bv[j] = bias[gn[j]];
  }

  // C/D layout: col = lane&15, row = (lane>>4)*4 + reg  [m89/m101, dtype-indep]
#pragma unroll
  for (int i = 0; i < 4; ++i) {
#pragma unroll
    for (int r = 0; r < 4; ++r) {
      int ml = i * 16 + kg * 4 + r;
      int gm = m0 + ml;
      float rs = row_scale[gm];
      float xvv[8];
#pragma unroll
      for (int o = 0; o < 8; ++o) xvv[o] = xsh[ml][o];
#pragma unroll
      for (int j = 0; j < 4; ++j) {
        int nl = j * 16 + lrow;
        float corr = 0.0f;
#pragma unroll
        for (int o = 0; o < 8; ++o) corr += xvv[o] * wsh[nl][o];
        for (int o = 8; o < cnt; ++o)   // generality fallback (cold in practice)
          corr += x[(size_t)gm * K_DIM + outlist[o]] *
                  w[(size_t)gn[j] * K_DIM + outlist[o]];
        float val = (float)acc[i][j][r] * rs * qs[j] + corr + bv[j];
        out[(size_t)gm * N_DIM + gn[j]] = val;
      }
    }
  }
}

// ---------------------------------------------------------------------------
extern "C" void kernel_launch(void* const* d_in, const int* in_sizes, int n_in,
                              void* d_out, int out_size, void* d_ws, size_t ws_size,
                              hipStream_t stream) {
  const float* x = (const float*)d_in[0];      // [M,K] fp32 (M = B*S)
  const float* w = (const float*)d_in[1];      // [N,K] fp32
  const float* bias = (const float*)d_in[2];   // [N]
  float* out = (float*)d_out;                  // [M,N] fp32
  const int M = in_sizes[0] / K_DIM;           // 4096

  // workspace layout (mask NOT zeroed: consumers test ==1 vs 0xAA poison)
  char* ws = (char*)d_ws;
  int* mask = (int*)(ws);                          // 16 KB
  int* count = (int*)(ws + 16384);                 // 4 B
  int* outlist = (int*)(ws + 20480);               // 16 KB
  float* row_scale = (float*)(ws + 36864);         // 16 KB
  float* q_scale = (float*)(ws + 53248);           // 16 KB
  int8_t* qx = (int8_t*)(ws + 131072);             // M*K int8 = 16 MB
  int8_t* qw = (int8_t*)(ws + 131072 + (size_t)M * K_DIM);  // N*K int8 = 16 MB

  k_rowquant<<<M / 4, 256, 0, stream>>>(x, row_scale, mask, qx);
  k_wquant<<<N_DIM / 4, 256, 0, stream>>>(w, mask, q_scale, qw, outlist, count);
  dim3 grid(N_DIM / 64, M / 64);
  k_gemm<<<grid, dim3(64, 1, 1), 0, stream>>>(qx, qw, row_scale, q_scale, bias,
                                              x, w, outlist, count, out);
}